// Round 5
// baseline (147.976 us; speedup 1.0000x reference)
//
#include <hip/hip_runtime.h>
#include <hip/hip_bf16.h>

static constexpr int BLOCK     = 256;
static constexpr int GRID_MAIN = 2048;

typedef float f32x4 __attribute__((ext_vector_type(4)));

__device__ __forceinline__ float patch_nan(float x) {
    return (x != x) ? 1e-6f : x;
}

// non-target term: -(1-alpha) * p^2 * ln(1-p)   (alpha = 0.25)
__device__ __forceinline__ float neg_term(float x) {
    return -0.75f * x * x * __logf(1.0f - x);
}

// target term: -alpha * (1-p)^2 * ln(p)
__device__ __forceinline__ float pos_term(float x) {
    float om = 1.0f - x;
    return -0.25f * om * om * __logf(x);
}

// Block-wide sum; result valid in thread 0 only.
__device__ __forceinline__ float block_reduce_sum(float v) {
    #pragma unroll
    for (int off = 32; off > 0; off >>= 1)
        v += __shfl_down(v, off, 64);
    __shared__ float smem[BLOCK / 64];
    const int lane = threadIdx.x & 63;
    const int wid  = threadIdx.x >> 6;
    if (lane == 0) smem[wid] = v;
    __syncthreads();
    float r = 0.0f;
    if (threadIdx.x == 0) {
        #pragma unroll
        for (int i = 0; i < BLOCK / 64; ++i) r += smem[i];
    }
    return r;
}

// Single fused kernel:
//  - streaming neg-term over every element (coalesced nt float4 loads)
//  - inline target-class correction (pos - neg at the target column)
//  - block partial -> d_ws; last block (threadfence/ticket) reduces the
//    2048 partials in index order (bit-deterministic) and writes the scalar.
__global__ void __launch_bounds__(BLOCK)
focal_fused(const f32x4* __restrict__ p4, const int* __restrict__ classes,
            float* __restrict__ partials, unsigned* __restrict__ ticket,
            float* __restrict__ out, int n4, int shiftC4, float invB) {
    float acc = 0.0f;
    const int maskC4 = (1 << shiftC4) - 1;
    const int S      = gridDim.x * blockDim.x;
    for (int i = blockIdx.x * blockDim.x + threadIdx.x; i < n4; i += S) {
        f32x4 v = __builtin_nontemporal_load(&p4[i]);
        float x0 = patch_nan(v.x), x1 = patch_nan(v.y);
        float x2 = patch_nan(v.z), x3 = patch_nan(v.w);
        acc += neg_term(x0);
        acc += neg_term(x1);
        acc += neg_term(x2);
        acc += neg_term(x3);
        const int row     = i >> shiftC4;
        const int colbase = (i & maskC4) << 2;
        const unsigned d  = (unsigned)(classes[row] - colbase);
        if (d < 4u) {  // target column falls inside this float4
            float x = (d == 0) ? x0 : (d == 1) ? x1 : (d == 2) ? x2 : x3;
            acc += pos_term(x) - neg_term(x);
        }
    }
    float r = block_reduce_sum(acc);

    __shared__ unsigned s_last;
    if (threadIdx.x == 0) {
        partials[blockIdx.x] = r;
        __threadfence();                      // release partial, device scope
        unsigned old = atomicAdd(ticket, 1u); // device-scope atomic
        s_last = (old == gridDim.x - 1) ? 1u : 0u;
        if (s_last) __threadfence();          // acquire before reading partials
    }
    __syncthreads();
    if (s_last) {
        float a = 0.0f;
        for (int i = threadIdx.x; i < (int)gridDim.x; i += blockDim.x)
            a += partials[i];
        float t = block_reduce_sum(a);
        if (threadIdx.x == 0) out[0] = t * invB;
    }
}

extern "C" void kernel_launch(void* const* d_in, const int* in_sizes, int n_in,
                              void* d_out, int out_size, void* d_ws, size_t ws_size,
                              hipStream_t stream) {
    const float* p       = (const float*)d_in[0];
    const int*   classes = (const int*)d_in[1];
    float*       out     = (float*)d_out;

    unsigned* ticket   = (unsigned*)d_ws;            // 1 word
    float*    partials = (float*)d_ws + 16;          // GRID_MAIN floats, 64B-aligned

    const long long N = (long long)in_sizes[0];   // B*C
    const int B  = in_sizes[1];
    const int C  = (int)(N / B);                  // 2048 (power of two)
    const int n4 = (int)(N / 4);
    const int c4 = C / 4;

    int shiftC4 = 0;
    while ((1 << shiftC4) < c4) ++shiftC4;        // log2(C/4) = 9

    hipMemsetAsync(ticket, 0, sizeof(unsigned), stream);  // capture-legal
    focal_fused<<<GRID_MAIN, BLOCK, 0, stream>>>((const f32x4*)p, classes,
                                                 partials, ticket, out,
                                                 n4, shiftC4, 1.0f / (float)B);
}

// Round 6
// 50.498 us; speedup vs baseline: 2.9304x; 2.9304x over previous
//
#include <hip/hip_runtime.h>
#include <hip/hip_bf16.h>

static constexpr int BLOCK     = 256;
static constexpr int GRID_MAIN = 2048;
static constexpr int MAX_RPB   = 32;   // max rows-per-block staged in LDS

typedef float f32x4 __attribute__((ext_vector_type(4)));

__device__ __forceinline__ float patch_nan(float x) {
    return (x != x) ? 1e-6f : x;
}

// non-target term: -(1-alpha) * p^2 * ln(1-p)   (alpha = 0.25)
__device__ __forceinline__ float neg_term(float x) {
    return -0.75f * x * x * __logf(1.0f - x);
}

// target term: -alpha * (1-p)^2 * ln(p)
__device__ __forceinline__ float pos_term(float x) {
    float om = 1.0f - x;
    return -0.25f * om * om * __logf(x);
}

// Block-wide sum; result valid in thread 0 only.
__device__ __forceinline__ float block_reduce_sum(float v) {
    #pragma unroll
    for (int off = 32; off > 0; off >>= 1)
        v += __shfl_down(v, off, 64);
    __shared__ float smem[BLOCK / 64];
    const int lane = threadIdx.x & 63;
    const int wid  = threadIdx.x >> 6;
    if (lane == 0) smem[wid] = v;
    __syncthreads();
    float r = 0.0f;
    if (threadIdx.x == 0) {
        #pragma unroll
        for (int i = 0; i < BLOCK / 64; ++i) r += smem[i];
    }
    return r;
}

// Specialized main pass: block b owns `rpb` contiguous rows (sequential
// 128 KB stream). Requires C/4 == 2*BLOCK (C == 2048): each thread loads
// 2 consecutive float4 per row (32 B/lane). Class indices staged in LDS
// once per block; per-row compare is an LDS broadcast, no global load.
__global__ void __launch_bounds__(BLOCK)
focal_rows(const f32x4* __restrict__ p4, const int* __restrict__ classes,
           float* __restrict__ partials, int c4, int rpb) {
    __shared__ int s_cls[MAX_RPB];
    const int row0 = blockIdx.x * rpb;
    if (threadIdx.x < rpb) s_cls[threadIdx.x] = classes[row0 + threadIdx.x];
    __syncthreads();

    const int tid = threadIdx.x;
    const f32x4* rp = p4 + (size_t)row0 * c4 + 2 * tid;
    float acc = 0.0f;

    for (int r = 0; r < rpb; ++r, rp += c4) {
        f32x4 v0 = rp[0];
        f32x4 v1 = rp[1];
        float x0 = patch_nan(v0.x), x1 = patch_nan(v0.y);
        float x2 = patch_nan(v0.z), x3 = patch_nan(v0.w);
        float x4 = patch_nan(v1.x), x5 = patch_nan(v1.y);
        float x6 = patch_nan(v1.z), x7 = patch_nan(v1.w);
        acc += neg_term(x0) + neg_term(x1) + neg_term(x2) + neg_term(x3);
        acc += neg_term(x4) + neg_term(x5) + neg_term(x6) + neg_term(x7);
        const unsigned d = (unsigned)(s_cls[r] - (tid << 3));
        if (d < 8u) {   // target column is one of this thread's 8 elements
            float x = (d == 0) ? x0 : (d == 1) ? x1 : (d == 2) ? x2 :
                      (d == 3) ? x3 : (d == 4) ? x4 : (d == 5) ? x5 :
                      (d == 6) ? x6 : x7;
            acc += pos_term(x) - neg_term(x);
        }
    }

    float r = block_reduce_sum(acc);
    if (threadIdx.x == 0) partials[blockIdx.x] = r;
}

// General fallback (round-3 structure): grid-stride float4 stream.
__global__ void __launch_bounds__(BLOCK)
focal_fused(const f32x4* __restrict__ p4, const int* __restrict__ classes,
            float* __restrict__ partials, int n4, int shiftC4) {
    float acc = 0.0f;
    const int maskC4 = (1 << shiftC4) - 1;
    const int S      = gridDim.x * blockDim.x;
    for (int i = blockIdx.x * blockDim.x + threadIdx.x; i < n4; i += S) {
        f32x4 v = p4[i];
        float x0 = patch_nan(v.x), x1 = patch_nan(v.y);
        float x2 = patch_nan(v.z), x3 = patch_nan(v.w);
        acc += neg_term(x0) + neg_term(x1) + neg_term(x2) + neg_term(x3);
        const int row     = i >> shiftC4;
        const int colbase = (i & maskC4) << 2;
        const unsigned d  = (unsigned)(classes[row] - colbase);
        if (d < 4u) {
            float x = (d == 0) ? x0 : (d == 1) ? x1 : (d == 2) ? x2 : x3;
            acc += pos_term(x) - neg_term(x);
        }
    }
    float r = block_reduce_sum(acc);
    if (threadIdx.x == 0) partials[blockIdx.x] = r;
}

// Deterministic final reduction of the partials, scale by 1/B.
__global__ void __launch_bounds__(BLOCK)
focal_final(const float* __restrict__ partials, int n,
            float* __restrict__ out, float invB) {
    float acc = 0.0f;
    for (int i = threadIdx.x; i < n; i += blockDim.x) acc += partials[i];
    float r = block_reduce_sum(acc);
    if (threadIdx.x == 0) out[0] = r * invB;
}

extern "C" void kernel_launch(void* const* d_in, const int* in_sizes, int n_in,
                              void* d_out, int out_size, void* d_ws, size_t ws_size,
                              hipStream_t stream) {
    const float* p       = (const float*)d_in[0];
    const int*   classes = (const int*)d_in[1];
    float*       out     = (float*)d_out;
    float*       ws      = (float*)d_ws;

    const long long N = (long long)in_sizes[0];   // B*C
    const int B  = in_sizes[1];
    const int C  = (int)(N / B);                  // 2048
    const int n4 = (int)(N / 4);
    const int c4 = C / 4;

    const int rpb = B / GRID_MAIN;                // 16
    const bool specialized = (c4 == 2 * BLOCK) && (B % GRID_MAIN == 0) &&
                             (rpb <= MAX_RPB);

    if (specialized) {
        focal_rows<<<GRID_MAIN, BLOCK, 0, stream>>>((const f32x4*)p, classes,
                                                    ws, c4, rpb);
    } else {
        int shiftC4 = 0;
        while ((1 << shiftC4) < c4) ++shiftC4;
        focal_fused<<<GRID_MAIN, BLOCK, 0, stream>>>((const f32x4*)p, classes,
                                                     ws, n4, shiftC4);
    }
    focal_final<<<1, BLOCK, 0, stream>>>(ws, GRID_MAIN, out, 1.0f / (float)B);
}